// Round 4
// baseline (258.284 us; speedup 1.0000x reference)
//
#include <hip/hip_runtime.h>

#define N_NODES 100000
#define N_EDGES 600000
#define K_DIM 128
#define M2 64
#define SCAN_BLOCKS ((N_NODES + 255) / 256)   // 391

using frag_ab = __attribute__((ext_vector_type(8))) short;   // 8 bf16 = 4 VGPRs
using frag_cd = __attribute__((ext_vector_type(4))) float;   // 4 fp32 acc

// liveness pin: forces the value materialized (batched vmcnt wait) and kept in VGPRs
#define PIN(x) asm volatile("" : "+v"(x))

// fp32 -> bf16 round-to-nearest-even
__device__ __forceinline__ unsigned short f2b(float f) {
  unsigned u = __builtin_bit_cast(unsigned, f);
  u = (u + 0x7fffu + ((u >> 16) & 1u)) >> 16;
  return (unsigned short)u;
}

// async global->LDS, 16 B per lane. LDS dest must be WAVE-UNIFORM (HW adds lane*16);
// global src is per-lane (swizzled LDS layouts = pre-swizzle the source).
__device__ __forceinline__ void gload_lds16(const void* gsrc, void* ldst) {
  __builtin_amdgcn_global_load_lds(
      (const __attribute__((address_space(1))) void*)gsrc,
      (__attribute__((address_space(3))) void*)ldst, 16, 0, 0);
}

// ---------------- fused: x->bf16 conversion + 4 weight transposes + degree count ----------------
#define XB_BLOCKS ((N_NODES * K_DIM / 4 + 255) / 256)            // 12500
#define W_ELEMS ((128 + 128 + 64 + 64) * 128)                    // 49152
#define WB_BLOCKS ((W_ELEMS + 255) / 256)                        // 192
#define DEG_BLOCKS ((N_EDGES + 255) / 256)                       // 2344
__global__ __launch_bounds__(256) void conv_all(const float* __restrict__ x,
                                                unsigned short* __restrict__ xb,
                                                const float* __restrict__ Ws1,
                                                const float* __restrict__ Wn1,
                                                const float* __restrict__ Ws2,
                                                const float* __restrict__ Wn2,
                                                unsigned short* __restrict__ Ws1T,
                                                unsigned short* __restrict__ Wn1T,
                                                unsigned short* __restrict__ Ws2T,
                                                unsigned short* __restrict__ Wn2T,
                                                const int* __restrict__ dst,
                                                int* __restrict__ deg) {
  if (blockIdx.x < XB_BLOCKS) {
    long i = (long)blockIdx.x * 256 + threadIdx.x;
    if (i >= (long)N_NODES * K_DIM / 4) return;
    float4 v = *(const float4*)(x + i * 4);
    ushort4 o;
    o.x = f2b(v.x); o.y = f2b(v.y); o.z = f2b(v.z); o.w = f2b(v.w);
    *(ushort4*)(xb + i * 4) = o;
  } else if (blockIdx.x < XB_BLOCKS + WB_BLOCKS) {
    int i = (blockIdx.x - XB_BLOCKS) * 256 + threadIdx.x;  // global weight elem
    if (i >= W_ELEMS) return;
    const float* W;
    unsigned short* WT;
    int M, li;
    if (i < 128 * 128)               { W = Ws1; WT = Ws1T; M = 128; li = i; }
    else if (i < 2 * 128 * 128)      { W = Wn1; WT = Wn1T; M = 128; li = i - 128 * 128; }
    else if (i < 2 * 128 * 128 + 64 * 128) { W = Ws2; WT = Ws2T; M = 64; li = i - 2 * 128 * 128; }
    else                             { W = Wn2; WT = Wn2T; M = 64; li = i - 2 * 128 * 128 - 64 * 128; }
    int n = li >> 7, k = li & 127;   // li = n*128 + k
    WT[li] = f2b(W[k * M + n]);
  } else {
    int e = (blockIdx.x - XB_BLOCKS - WB_BLOCKS) * 256 + threadIdx.x;
    if (e < N_EDGES) atomicAdd(&deg[dst[e]], 1);
  }
}

// ---------------- scan stage 1: per-256-block exclusive partials + block sums ----------------
__global__ __launch_bounds__(256) void scan1(const int* __restrict__ deg,
                                             int* __restrict__ partial,
                                             int* __restrict__ blockSums, int n) {
  __shared__ int sdata[256];
  int tid = threadIdx.x;
  int i = blockIdx.x * 256 + tid;
  int v = (i < n) ? deg[i] : 0;
  sdata[tid] = v;
  __syncthreads();
#pragma unroll
  for (int off = 1; off < 256; off <<= 1) {
    int t = (tid >= off) ? sdata[tid - off] : 0;
    __syncthreads();
    sdata[tid] += t;
    __syncthreads();
  }
  if (i < n) partial[i] = sdata[tid] - v;
  if (tid == 255) blockSums[blockIdx.x] = sdata[255];
}

// ---------------- scan stage 2: every block redundantly scans blockSums, finalizes slice ----------------
__global__ __launch_bounds__(512) void scanB(int* __restrict__ row_ptr,   // partial in, full out
                                             const int* __restrict__ blockSums,
                                             int* __restrict__ cursor, int n, int nE) {
  __shared__ int bs[512];
  int tid = threadIdx.x;
  int v = (tid < SCAN_BLOCKS) ? blockSums[tid] : 0;
  bs[tid] = v;
  __syncthreads();
#pragma unroll
  for (int off = 1; off < 512; off <<= 1) {
    int t = (tid >= off) ? bs[tid - off] : 0;
    __syncthreads();
    bs[tid] += t;
    __syncthreads();
  }
  bs[tid] -= v;
  __syncthreads();

  int i = blockIdx.x * 512 + tid;
  if (i < n) {
    int val = row_ptr[i] + bs[i >> 8];
    row_ptr[i] = val;
    cursor[i] = val;
  }
  if (i == 0) row_ptr[n] = nE;
}

// ---------------- CSR fill ----------------
__global__ __launch_bounds__(256) void csr_fill(const int* __restrict__ src,
                                                const int* __restrict__ dst,
                                                int* __restrict__ cursor,
                                                int* __restrict__ csr_src, int nE) {
  int e = blockIdx.x * blockDim.x + threadIdx.x;
  if (e < nE) {
    int pos = atomicAdd(&cursor[dst[e]], 1);
    csr_src[pos] = src[e];
  }
}

// ---------------- gather-mean, 128 bf16 cols: 16 threads/node, 8-wide predicated batches ----------------
__global__ __launch_bounds__(256) void aggregate128(const unsigned short* __restrict__ xb,
                                                    const int* __restrict__ row_ptr,
                                                    const int* __restrict__ csr_src,
                                                    unsigned short* __restrict__ agg, int n) {
  int t = blockIdx.x * blockDim.x + threadIdx.x;
  int node = t >> 4;
  int c = (t & 15) << 3;  // 8 bf16 per thread
  if (node >= n) return;
  int beg = row_ptr[node], end = row_ptr[node + 1];
  float acc[8];
#pragma unroll
  for (int j = 0; j < 8; ++j) acc[j] = 0.f;

  if (end > beg) {
    for (int e0 = beg; e0 < end; e0 += 8) {
      int idx[8];
#pragma unroll
      for (int p = 0; p < 8; ++p) idx[p] = csr_src[min(e0 + p, end - 1)];
      uint4 v[8];
#pragma unroll
      for (int p = 0; p < 8; ++p) v[p] = *(const uint4*)(xb + (size_t)idx[p] * K_DIM + c);
#pragma unroll
      for (int p = 0; p < 8; ++p) {
        float m = (e0 + p < end) ? 1.f : 0.f;
        unsigned u[4] = {v[p].x, v[p].y, v[p].z, v[p].w};
#pragma unroll
        for (int j = 0; j < 4; ++j) {
          acc[2 * j]     += m * __builtin_bit_cast(float, u[j] << 16);
          acc[2 * j + 1] += m * __builtin_bit_cast(float, u[j] & 0xffff0000u);
        }
      }
    }
  }
  float inv = 1.0f / (float)max(end - beg, 1);
  uint4 o;
  unsigned* op = (unsigned*)&o;
#pragma unroll
  for (int j = 0; j < 4; ++j) {
    unsigned lo = f2b(acc[2 * j] * inv);
    unsigned hi = f2b(acc[2 * j + 1] * inv);
    op[j] = lo | (hi << 16);
  }
  *(uint4*)(agg + (size_t)node * K_DIM + c) = o;
}

// ---------------- gather-mean-add, 64 bf16 cols -> out fp32: 8 threads/node, 8-wide batches ----------------
__global__ __launch_bounds__(256) void aggregate64_add(const unsigned short* __restrict__ g,
                                                       const int* __restrict__ row_ptr,
                                                       const int* __restrict__ csr_src,
                                                       float* __restrict__ out, int n) {
  int t = blockIdx.x * blockDim.x + threadIdx.x;
  int node = t >> 3;
  int c = (t & 7) << 3;  // 8 bf16 per thread
  if (node >= n) return;
  int beg = row_ptr[node], end = row_ptr[node + 1];
  float acc[8];
#pragma unroll
  for (int j = 0; j < 8; ++j) acc[j] = 0.f;

  if (end > beg) {
    for (int e0 = beg; e0 < end; e0 += 8) {
      int idx[8];
#pragma unroll
      for (int p = 0; p < 8; ++p) idx[p] = csr_src[min(e0 + p, end - 1)];
      uint4 v[8];
#pragma unroll
      for (int p = 0; p < 8; ++p) v[p] = *(const uint4*)(g + (size_t)idx[p] * M2 + c);
#pragma unroll
      for (int p = 0; p < 8; ++p) {
        float m = (e0 + p < end) ? 1.f : 0.f;
        unsigned u[4] = {v[p].x, v[p].y, v[p].z, v[p].w};
#pragma unroll
        for (int j = 0; j < 4; ++j) {
          acc[2 * j]     += m * __builtin_bit_cast(float, u[j] << 16);
          acc[2 * j + 1] += m * __builtin_bit_cast(float, u[j] & 0xffff0000u);
        }
      }
    }
  }
  float inv = 1.0f / (float)max(end - beg, 1);
  float* op = out + (size_t)node * M2 + c;
  float4 o0 = *(float4*)(op);
  float4 o1 = *(float4*)(op + 4);
  o0.x += acc[0] * inv; o0.y += acc[1] * inv; o0.z += acc[2] * inv; o0.w += acc[3] * inv;
  o1.x += acc[4] * inv; o1.y += acc[5] * inv; o1.z += acc[6] * inv; o1.w += acc[7] * inv;
  *(float4*)(op) = o0;
  *(float4*)(op + 4) = o1;
}

// ---------------- fused both-layer GEMM, 64-node blocks (v4: weights via LDS) ----------------
// History: v1 reg-prefetch 52.9us / v2 smaller tile 61us / v3 x,agg via DMA-LDS 41.5us.
// v3 counters (VGPR=92, MfmaUtil 8%) showed the remaining serializer: 48 weight frags/wave
// loaded one-at-a-time from L2 inside the MFMA chain (~48 x 400cy exposed latency).
// v4: W1 (Ws1T+Wn1T, 64KB) DMA'd to LDS per block (L2-hot source), read via ds_read_b128
// which the compiler pipelines with fine lgkmcnt; x/agg + W2 go global->VGPR with PIN()
// (asm liveness pin) so their loads issue as one batch with one counted vmcnt wait.
// LDS 80KB = W1 64K + h1 16K -> 2 blocks/CU. XOR swizzle (byte ^= (row&7)<<4) everywhere,
// applied on the DMA's global source (LDS dest linear) and on all ds reads/writes.
__global__ __launch_bounds__(256, 2) void sage_fused_gemm(const unsigned short* __restrict__ xb,
                                                          const unsigned short* __restrict__ aggb,
                                                          const unsigned short* __restrict__ Ws1T,
                                                          const unsigned short* __restrict__ Wn1T,
                                                          const float* __restrict__ b1,
                                                          const unsigned short* __restrict__ Ws2T,
                                                          const unsigned short* __restrict__ Wn2T,
                                                          const float* __restrict__ b2,
                                                          float* __restrict__ out,
                                                          unsigned short* __restrict__ g, int N) {
  // [0,32K): Ws1T  [32K,64K): Wn1T  [64K,80K): h1 (64 nodes x 256B)
  __shared__ unsigned short sW[40960];

  const int tid = threadIdx.x;
  const int wave = tid >> 6;
  const int lane = tid & 63;
  const int l15 = lane & 15;
  const int q = lane >> 4;
  const int nodehalf = wave >> 1;  // 32-node slice
  const int fhalf = wave & 1;      // 64-feat slice (phase 1) / output matrix (phase 2)
  const int nbase_l = nodehalf * 32;
  const int nbase_g = blockIdx.x * 64 + nbase_l;
  const int fbase = fhalf * 64;

  // ---- x/agg fragments: global->VGPR, issued first (HBM/L3 latency hides under DMA) ----
  frag_ab ax[2][4], ag[2][4];
#pragma unroll
  for (int nt = 0; nt < 2; ++nt) {
    int m = nbase_g + nt * 16 + l15;
    int mc = (m < N) ? m : (N - 1);
    const unsigned short* xr = xb + (size_t)mc * K_DIM + q * 8;
    const unsigned short* gr = aggb + (size_t)mc * K_DIM + q * 8;
#pragma unroll
    for (int kb = 0; kb < 4; ++kb) {
      ax[nt][kb] = *(const frag_ab*)(xr + kb * 32);
      ag[nt][kb] = *(const frag_ab*)(gr + kb * 32);
    }
  }

  // ---- DMA W1 into LDS: 2 x 32KB, pre-swizzled global source, linear LDS dest ----
  char* lb = (char*)sW;
#pragma unroll
  for (int it = 0; it < 8; ++it) {
    int L = it * 4096 + tid * 16;              // linear LDS byte within a 32KB half
    int f = L >> 8;                            // weight row (feat)
    int srb = (L & 255) ^ ((f & 7) << 4);      // inverse-swizzled source byte in row
    const char* g1 = (const char*)Ws1T + f * 256 + srb;
    const char* g2 = (const char*)Wn1T + f * 256 + srb;
    char* d = lb + it * 4096 + wave * 1024;    // wave-uniform; HW adds lane*16
    gload_lds16(g1, d);
    gload_lds16(g2, d + 32768);
  }

  // pin x/agg frags: one batched vmcnt wait, then they stay resident in VGPRs
#pragma unroll
  for (int nt = 0; nt < 2; ++nt)
#pragma unroll
    for (int kb = 0; kb < 4; ++kb) { PIN(ax[nt][kb]); PIN(ag[nt][kb]); }

  __syncthreads();  // drains DMA

  // ---- phase 1: W1 frags from LDS (pipelined lgkmcnt), MFMA against resident x/agg ----
  frag_cd acc[2][4];  // [nt][ft]
#pragma unroll
  for (int nt = 0; nt < 2; ++nt)
#pragma unroll
    for (int ft = 0; ft < 4; ++ft) acc[nt][ft] = (frag_cd)(0.f);

#pragma unroll
  for (int kb = 0; kb < 4; ++kb) {
    frag_ab fs[4], fn[4];
#pragma unroll
    for (int ft = 0; ft < 4; ++ft) {
      int r = fbase + ft * 16 + l15;
      int off = (kb * 64 + q * 16) ^ ((r & 7) << 4);
      const char* p = (const char*)sW + r * 256 + off;
      fs[ft] = *(const frag_ab*)p;
      fn[ft] = *(const frag_ab*)(p + 32768);
    }
#pragma unroll
    for (int ft = 0; ft < 4; ++ft)
#pragma unroll
      for (int nt = 0; nt < 2; ++nt) {
        acc[nt][ft] = __builtin_amdgcn_mfma_f32_16x16x32_bf16(fs[ft], ax[nt][kb], acc[nt][ft], 0, 0, 0);
        acc[nt][ft] = __builtin_amdgcn_mfma_f32_16x16x32_bf16(fn[ft], ag[nt][kb], acc[nt][ft], 0, 0, 0);
      }
  }

  // ---- epilogue 1: relu(acc + b1) -> h1 LDS region (same swizzle) ----
#pragma unroll
  for (int ft = 0; ft < 4; ++ft) {
    int f0 = fbase + ft * 16 + q * 4;
    float4 bv = *(const float4*)(b1 + f0);
#pragma unroll
    for (int nt = 0; nt < 2; ++nt) {
      int nl = nbase_l + nt * 16 + l15;
      ushort4 o;
      o.x = f2b(fmaxf(acc[nt][ft][0] + bv.x, 0.f));
      o.y = f2b(fmaxf(acc[nt][ft][1] + bv.y, 0.f));
      o.z = f2b(fmaxf(acc[nt][ft][2] + bv.z, 0.f));
      o.w = f2b(fmaxf(acc[nt][ft][3] + bv.w, 0.f));
      int b = (f0 * 2) ^ ((nl & 7) << 4);
      *(ushort4*)((char*)sW + 65536 + nl * 256 + b) = o;
    }
  }

  // ---- W2 frags: global->VGPR in phase-1's shadow, pinned before the barrier ----
  const unsigned short* W2 = fhalf ? Wn2T : Ws2T;  // wave's output matrix
  const unsigned short* wp2 = W2 + (size_t)l15 * K_DIM + q * 8;
  frag_ab w2f[4][4];
#pragma unroll
  for (int kb = 0; kb < 4; ++kb)
#pragma unroll
    for (int ft = 0; ft < 4; ++ft)
      w2f[kb][ft] = *(const frag_ab*)(wp2 + ft * (16 * K_DIM) + kb * 32);
#pragma unroll
  for (int kb = 0; kb < 4; ++kb)
#pragma unroll
    for (int ft = 0; ft < 4; ++ft) PIN(w2f[kb][ft]);

  __syncthreads();  // h1 visible across waves (sibling fhalf wrote other feat half)

  // ---- phase 2: h1 frags from LDS ----
  frag_cd acc2[2][4];
#pragma unroll
  for (int nt = 0; nt < 2; ++nt)
#pragma unroll
    for (int ft = 0; ft < 4; ++ft) acc2[nt][ft] = (frag_cd)(0.f);

#pragma unroll
  for (int kb = 0; kb < 4; ++kb) {
    frag_ab ah[2];
#pragma unroll
    for (int nt = 0; nt < 2; ++nt) {
      int r = nbase_l + nt * 16 + l15;
      int off = (kb * 64 + q * 16) ^ ((r & 7) << 4);
      ah[nt] = *(const frag_ab*)((const char*)sW + 65536 + r * 256 + off);
    }
#pragma unroll
    for (int ft = 0; ft < 4; ++ft)
#pragma unroll
      for (int nt = 0; nt < 2; ++nt)
        acc2[nt][ft] = __builtin_amdgcn_mfma_f32_16x16x32_bf16(w2f[kb][ft], ah[nt], acc2[nt][ft], 0, 0, 0);
  }

  // ---- epilogue 2: fhalf==0 -> out fp32 (+b2), fhalf==1 -> g bf16 ----
  if (fhalf == 0) {
#pragma unroll
    for (int ft = 0; ft < 4; ++ft) {
      int f0 = ft * 16 + q * 4;
      float4 bv = *(const float4*)(b2 + f0);
#pragma unroll
      for (int nt = 0; nt < 2; ++nt) {
        int node = nbase_g + nt * 16 + l15;
        if (node < N) {
          float4 o;
          o.x = acc2[nt][ft][0] + bv.x;
          o.y = acc2[nt][ft][1] + bv.y;
          o.z = acc2[nt][ft][2] + bv.z;
          o.w = acc2[nt][ft][3] + bv.w;
          *(float4*)(out + (size_t)node * M2 + f0) = o;
        }
      }
    }
  } else {
#pragma unroll
    for (int ft = 0; ft < 4; ++ft) {
      int f0 = ft * 16 + q * 4;
#pragma unroll
      for (int nt = 0; nt < 2; ++nt) {
        int node = nbase_g + nt * 16 + l15;
        if (node < N) {
          ushort4 o;
          o.x = f2b(acc2[nt][ft][0]);
          o.y = f2b(acc2[nt][ft][1]);
          o.z = f2b(acc2[nt][ft][2]);
          o.w = f2b(acc2[nt][ft][3]);
          *(ushort4*)(g + (size_t)node * M2 + f0) = o;
        }
      }
    }
  }
}

extern "C" void kernel_launch(void* const* d_in, const int* in_sizes, int n_in,
                              void* d_out, int out_size, void* d_ws, size_t ws_size,
                              hipStream_t stream) {
  const float* x   = (const float*)d_in[0];
  const int*   src = (const int*)d_in[1];
  const int*   dst = (const int*)d_in[2];
  const float* Ws1 = (const float*)d_in[3];
  const float* Wn1 = (const float*)d_in[4];
  const float* b1  = (const float*)d_in[5];
  const float* Ws2 = (const float*)d_in[6];
  const float* Wn2 = (const float*)d_in[7];
  const float* b2  = (const float*)d_in[8];
  float* out = (float*)d_out;

  char* ws = (char*)d_ws;
  size_t off = 0;
  auto alloc = [&](size_t bytes) {
    void* p = ws + off;
    off = (off + bytes + 4095) & ~(size_t)4095;
    return p;
  };
  int* deg       = (int*)alloc((size_t)N_NODES * 4);
  int* row_ptr   = (int*)alloc((size_t)(N_NODES + 1) * 4);
  int* cursor    = (int*)alloc((size_t)N_NODES * 4);
  int* blockSums = (int*)alloc(512 * 4);
  int* csr_src   = (int*)alloc((size_t)N_EDGES * 4);
  unsigned short* xb   = (unsigned short*)alloc((size_t)N_NODES * K_DIM * 2);
  unsigned short* aggb = (unsigned short*)alloc((size_t)N_NODES * K_DIM * 2);
  unsigned short* g    = (unsigned short*)alloc((size_t)N_NODES * M2 * 2);
  unsigned short* Ws1T = (unsigned short*)alloc((size_t)128 * 128 * 2);
  unsigned short* Wn1T = (unsigned short*)alloc((size_t)128 * 128 * 2);
  unsigned short* Ws2T = (unsigned short*)alloc((size_t)64 * 128 * 2);
  unsigned short* Wn2T = (unsigned short*)alloc((size_t)64 * 128 * 2);

  hipMemsetAsync(deg, 0, (size_t)N_NODES * 4, stream);

  // fused conversions (x -> bf16, weight transposes) + degree count
  conv_all<<<XB_BLOCKS + WB_BLOCKS + DEG_BLOCKS, 256, 0, stream>>>(
      x, xb, Ws1, Wn1, Ws2, Wn2, Ws1T, Wn1T, Ws2T, Wn2T, dst, deg);

  // CSR build: 2-stage scan -> fill
  scan1<<<SCAN_BLOCKS, 256, 0, stream>>>(deg, row_ptr, blockSums, N_NODES);
  scanB<<<(N_NODES + 511) / 512, 512, 0, stream>>>(row_ptr, blockSums, cursor, N_NODES, N_EDGES);
  csr_fill<<<(N_EDGES + 255) / 256, 256, 0, stream>>>(src, dst, cursor, csr_src, N_EDGES);

  // layer-1 aggregation (gather-mean, 8-wide predicated batches)
  {
    long t = (long)N_NODES * 16;
    aggregate128<<<(int)((t + 255) / 256), 256, 0, stream>>>(xb, row_ptr, csr_src, aggb, N_NODES);
  }

  // fused layer-1 + layer-2 GEMMs (W1 via LDS, x/agg/W2 pinned in VGPRs), 64 nodes/block
  sage_fused_gemm<<<(N_NODES + 63) / 64, 256, 0, stream>>>(
      xb, aggb, Ws1T, Wn1T, b1, Ws2T, Wn2T, b2, out, g, N_NODES);

  // layer-2 aggregation (adds mean(g) into out)
  {
    long t = (long)N_NODES * 8;
    aggregate64_add<<<(int)((t + 255) / 256), 256, 0, stream>>>(g, row_ptr, csr_src, out, N_NODES);
  }
}

// Round 6
// 241.051 us; speedup vs baseline: 1.0715x; 1.0715x over previous
//
#include <hip/hip_runtime.h>

#define N_NODES 100000
#define N_EDGES 600000
#define K_DIM 128
#define M2 64
#define SCAN_BLOCKS ((N_NODES + 255) / 256)   // 391
#define NT_TILES ((N_NODES + 63) / 64)        // 1563 64-node tiles
#define GEMM_GRID 256

using frag_ab = __attribute__((ext_vector_type(8))) short;   // 8 bf16 = 4 VGPRs
using frag_cd = __attribute__((ext_vector_type(4))) float;   // 4 fp32 acc

// fp32 -> bf16 round-to-nearest-even
__device__ __forceinline__ unsigned short f2b(float f) {
  unsigned u = __builtin_bit_cast(unsigned, f);
  u = (u + 0x7fffu + ((u >> 16) & 1u)) >> 16;
  return (unsigned short)u;
}

// async global->LDS, 16 B per lane. LDS dest wave-uniform (HW adds lane*16);
// global src per-lane (swizzled LDS layouts = pre-swizzle the source).
__device__ __forceinline__ void gload_lds16(const void* gsrc, void* ldst) {
  __builtin_amdgcn_global_load_lds(
      (const __attribute__((address_space(1))) void*)gsrc,
      (__attribute__((address_space(3))) void*)ldst, 16, 0, 0);
}

// raw barrier: drain LDS ops only, keep DMA/stores (vmcnt) in flight
__device__ __forceinline__ void lgkm_barrier() {
  __builtin_amdgcn_sched_barrier(0);
  asm volatile("s_waitcnt lgkmcnt(0)" ::: "memory");
  __builtin_amdgcn_s_barrier();
  __builtin_amdgcn_sched_barrier(0);
}

// ---------------- fused: x->bf16 conversion + 4 weight transposes + degree count ----------------
#define XB_BLOCKS ((N_NODES * K_DIM / 4 + 255) / 256)            // 12500
#define W_ELEMS ((128 + 128 + 64 + 64) * 128)                    // 49152
#define WB_BLOCKS ((W_ELEMS + 255) / 256)                        // 192
#define DEG_BLOCKS ((N_EDGES + 255) / 256)                       // 2344
__global__ __launch_bounds__(256) void conv_all(const float* __restrict__ x,
                                                unsigned short* __restrict__ xb,
                                                const float* __restrict__ Ws1,
                                                const float* __restrict__ Wn1,
                                                const float* __restrict__ Ws2,
                                                const float* __restrict__ Wn2,
                                                unsigned short* __restrict__ Ws1T,
                                                unsigned short* __restrict__ Wn1T,
                                                unsigned short* __restrict__ Ws2T,
                                                unsigned short* __restrict__ Wn2T,
                                                const int* __restrict__ dst,
                                                int* __restrict__ deg) {
  if (blockIdx.x < XB_BLOCKS) {
    long i = (long)blockIdx.x * 256 + threadIdx.x;
    if (i >= (long)N_NODES * K_DIM / 4) return;
    float4 v = *(const float4*)(x + i * 4);
    ushort4 o;
    o.x = f2b(v.x); o.y = f2b(v.y); o.z = f2b(v.z); o.w = f2b(v.w);
    *(ushort4*)(xb + i * 4) = o;
  } else if (blockIdx.x < XB_BLOCKS + WB_BLOCKS) {
    int i = (blockIdx.x - XB_BLOCKS) * 256 + threadIdx.x;  // global weight elem
    if (i >= W_ELEMS) return;
    const float* W;
    unsigned short* WT;
    int M, li;
    if (i < 128 * 128)               { W = Ws1; WT = Ws1T; M = 128; li = i; }
    else if (i < 2 * 128 * 128)      { W = Wn1; WT = Wn1T; M = 128; li = i - 128 * 128; }
    else if (i < 2 * 128 * 128 + 64 * 128) { W = Ws2; WT = Ws2T; M = 64; li = i - 2 * 128 * 128; }
    else                             { W = Wn2; WT = Wn2T; M = 64; li = i - 2 * 128 * 128 - 64 * 128; }
    int n = li >> 7, k = li & 127;   // li = n*128 + k
    WT[li] = f2b(W[k * M + n]);
  } else {
    int e = (blockIdx.x - XB_BLOCKS - WB_BLOCKS) * 256 + threadIdx.x;
    if (e < N_EDGES) atomicAdd(&deg[dst[e]], 1);
  }
}

// ---------------- scan stage 1: per-256-block exclusive partials + block sums ----------------
__global__ __launch_bounds__(256) void scan1(const int* __restrict__ deg,
                                             int* __restrict__ partial,
                                             int* __restrict__ blockSums, int n) {
  __shared__ int sdata[256];
  int tid = threadIdx.x;
  int i = blockIdx.x * 256 + tid;
  int v = (i < n) ? deg[i] : 0;
  sdata[tid] = v;
  __syncthreads();
#pragma unroll
  for (int off = 1; off < 256; off <<= 1) {
    int t = (tid >= off) ? sdata[tid - off] : 0;
    __syncthreads();
    sdata[tid] += t;
    __syncthreads();
  }
  if (i < n) partial[i] = sdata[tid] - v;
  if (tid == 255) blockSums[blockIdx.x] = sdata[255];
}

// ---------------- scan stage 2: every block redundantly scans blockSums, finalizes slice ----------------
__global__ __launch_bounds__(512) void scanB(int* __restrict__ row_ptr,   // partial in, full out
                                             const int* __restrict__ blockSums,
                                             int* __restrict__ cursor, int n, int nE) {
  __shared__ int bs[512];
  int tid = threadIdx.x;
  int v = (tid < SCAN_BLOCKS) ? blockSums[tid] : 0;
  bs[tid] = v;
  __syncthreads();
#pragma unroll
  for (int off = 1; off < 512; off <<= 1) {
    int t = (tid >= off) ? bs[tid - off] : 0;
    __syncthreads();
    bs[tid] += t;
    __syncthreads();
  }
  bs[tid] -= v;
  __syncthreads();

  int i = blockIdx.x * 512 + tid;
  if (i < n) {
    int val = row_ptr[i] + bs[i >> 8];
    row_ptr[i] = val;
    cursor[i] = val;
  }
  if (i == 0) row_ptr[n] = nE;
}

// ---------------- CSR fill ----------------
__global__ __launch_bounds__(256) void csr_fill(const int* __restrict__ src,
                                                const int* __restrict__ dst,
                                                int* __restrict__ cursor,
                                                int* __restrict__ csr_src, int nE) {
  int e = blockIdx.x * blockDim.x + threadIdx.x;
  if (e < nE) {
    int pos = atomicAdd(&cursor[dst[e]], 1);
    csr_src[pos] = src[e];
  }
}

// ---------------- gather-mean, 128 bf16 cols: 16 threads/node, 8-wide predicated batches ----------------
__global__ __launch_bounds__(256) void aggregate128(const unsigned short* __restrict__ xb,
                                                    const int* __restrict__ row_ptr,
                                                    const int* __restrict__ csr_src,
                                                    unsigned short* __restrict__ agg, int n) {
  int t = blockIdx.x * blockDim.x + threadIdx.x;
  int node = t >> 4;
  int c = (t & 15) << 3;  // 8 bf16 per thread
  if (node >= n) return;
  int beg = row_ptr[node], end = row_ptr[node + 1];
  float acc[8];
#pragma unroll
  for (int j = 0; j < 8; ++j) acc[j] = 0.f;

  if (end > beg) {
    for (int e0 = beg; e0 < end; e0 += 8) {
      int idx[8];
#pragma unroll
      for (int p = 0; p < 8; ++p) idx[p] = csr_src[min(e0 + p, end - 1)];
      uint4 v[8];
#pragma unroll
      for (int p = 0; p < 8; ++p) v[p] = *(const uint4*)(xb + (size_t)idx[p] * K_DIM + c);
#pragma unroll
      for (int p = 0; p < 8; ++p) {
        float m = (e0 + p < end) ? 1.f : 0.f;
        unsigned u[4] = {v[p].x, v[p].y, v[p].z, v[p].w};
#pragma unroll
        for (int j = 0; j < 4; ++j) {
          acc[2 * j]     += m * __builtin_bit_cast(float, u[j] << 16);
          acc[2 * j + 1] += m * __builtin_bit_cast(float, u[j] & 0xffff0000u);
        }
      }
    }
  }
  float inv = 1.0f / (float)max(end - beg, 1);
  uint4 o;
  unsigned* op = (unsigned*)&o;
#pragma unroll
  for (int j = 0; j < 4; ++j) {
    unsigned lo = f2b(acc[2 * j] * inv);
    unsigned hi = f2b(acc[2 * j + 1] * inv);
    op[j] = lo | (hi << 16);
  }
  *(uint4*)(agg + (size_t)node * K_DIM + c) = o;
}

// ---------------- gather-mean-add, 64 bf16 cols -> out fp32: 8 threads/node, 8-wide batches ----------------
__global__ __launch_bounds__(256) void aggregate64_add(const unsigned short* __restrict__ g,
                                                       const int* __restrict__ row_ptr,
                                                       const int* __restrict__ csr_src,
                                                       float* __restrict__ out, int n) {
  int t = blockIdx.x * blockDim.x + threadIdx.x;
  int node = t >> 3;
  int c = (t & 7) << 3;  // 8 bf16 per thread
  if (node >= n) return;
  int beg = row_ptr[node], end = row_ptr[node + 1];
  float acc[8];
#pragma unroll
  for (int j = 0; j < 8; ++j) acc[j] = 0.f;

  if (end > beg) {
    for (int e0 = beg; e0 < end; e0 += 8) {
      int idx[8];
#pragma unroll
      for (int p = 0; p < 8; ++p) idx[p] = csr_src[min(e0 + p, end - 1)];
      uint4 v[8];
#pragma unroll
      for (int p = 0; p < 8; ++p) v[p] = *(const uint4*)(g + (size_t)idx[p] * M2 + c);
#pragma unroll
      for (int p = 0; p < 8; ++p) {
        float m = (e0 + p < end) ? 1.f : 0.f;
        unsigned u[4] = {v[p].x, v[p].y, v[p].z, v[p].w};
#pragma unroll
        for (int j = 0; j < 4; ++j) {
          acc[2 * j]     += m * __builtin_bit_cast(float, u[j] << 16);
          acc[2 * j + 1] += m * __builtin_bit_cast(float, u[j] & 0xffff0000u);
        }
      }
    }
  }
  float inv = 1.0f / (float)max(end - beg, 1);
  float* op = out + (size_t)node * M2 + c;
  float4 o0 = *(float4*)(op);
  float4 o1 = *(float4*)(op + 4);
  o0.x += acc[0] * inv; o0.y += acc[1] * inv; o0.z += acc[2] * inv; o0.w += acc[3] * inv;
  o1.x += acc[4] * inv; o1.y += acc[5] * inv; o1.z += acc[6] * inv; o1.w += acc[7] * inv;
  *(float4*)(op) = o0;
  *(float4*)(op + 4) = o1;
}

// stage one 64-node tile of x+agg (32 KB) into LDS dbuf half, swizzled source
__device__ __forceinline__ void stage_tile(const unsigned short* xb, const unsigned short* aggb,
                                           int t, char* dstbase, int tid, int wave, int N) {
#pragma unroll
  for (int it = 0; it < 2; ++it) {
    int L = it * 8192 + tid * 16;            // [0, 16384)
    int row = L >> 8;                        // 0..63
    int srb = (L & 255) ^ ((row & 7) << 4);  // inverse-swizzled source byte
    int node = t * 64 + row;
    if (node >= N) node = N - 1;             // clamp (garbage rows never stored)
    char* d = dstbase + it * 8192 + wave * 1024;  // wave-uniform; HW adds lane*16
    gload_lds16((const char*)xb + (size_t)node * 256 + srb, d);
    gload_lds16((const char*)aggb + (size_t)node * 256 + srb, d + 16384);
  }
}

// ---------------- fused both-layer GEMM (v5: persistent, everything via DMA+LDS) ----------------
// v1/v2: reg-prefetch -> compiler serialized loads (52/61us). v3: x/agg via DMA-LDS -> 41.5us,
// W1 frags still serialized. v4: W1 via LDS but x/agg+W2 via reg+PIN -> scheduler paired
// load+pin = one-at-a-time waits, 45.5us, VGPR=88. Invariant: ANY global->VGPR operand load
// gets latency-serialized. v5 removes them all: persistent blocks (grid=256, 1/CU, 512 thr),
// weights staged ONCE (W1 64K + W2 32K), x/agg 2x32K double-buffer with one-tile-ahead DMA;
// raw lgkm-only barriers inside the iteration keep the prefetch DMA in flight (counted-vmcnt
// principle); the only vmcnt(0) drain is the per-iteration __syncthreads, which IS the HBM wait.
// LDS = 160KB exactly. h1 overlays the consumed x region. XOR swizzle (byte^=(row&7)<<4) on
// all 256B-row tiles, applied via pre-swizzled DMA source + swizzled ds accesses.
// (biases are plain loads, hoisted by the compiler; v5a removed the PIN — backend can't
// handle tied indirect 128-bit asm operands, and PIN pairing serializes loads anyway.)
__global__ __launch_bounds__(512, 2) void sage_fused_gemm(const unsigned short* __restrict__ xb,
                                                          const unsigned short* __restrict__ aggb,
                                                          const unsigned short* __restrict__ Ws1T,
                                                          const unsigned short* __restrict__ Wn1T,
                                                          const float* __restrict__ b1,
                                                          const unsigned short* __restrict__ Ws2T,
                                                          const unsigned short* __restrict__ Wn2T,
                                                          const float* __restrict__ b2,
                                                          float* __restrict__ out,
                                                          unsigned short* __restrict__ g, int N) {
  // [0,32K) Ws1T | [32K,64K) Wn1T | [64K,80K) Ws2T | [80K,96K) Wn2T | [96K,128K) buf0 | [128K,160K) buf1
  // each buf: x rows 0..63 (16K) then agg rows (16K); h1 overlays the x region after phase 1.
  __shared__ char sL[163840];

  const int tid = threadIdx.x;
  const int wave = tid >> 6;
  const int lane = tid & 63;
  const int l15 = lane & 15;
  const int q = lane >> 4;
  const int nodeq = wave >> 1;     // 0..3 -> 16-node strip
  const int fhalf = wave & 1;      // phase-1 feat half / phase-2 output matrix
  const int fbase = fhalf * 64;

  // ---- prologue: stage all weights (96 KB) + first tile (once per block) ----
#pragma unroll
  for (int it = 0; it < 4; ++it) {           // W1: 2 x 32K
    int L = it * 8192 + tid * 16;
    int row = L >> 8;
    int srb = (L & 255) ^ ((row & 7) << 4);
    char* d = sL + it * 8192 + wave * 1024;
    gload_lds16((const char*)Ws1T + row * 256 + srb, d);
    gload_lds16((const char*)Wn1T + row * 256 + srb, d + 32768);
  }
#pragma unroll
  for (int it = 0; it < 2; ++it) {           // W2: 2 x 16K
    int L = it * 8192 + tid * 16;
    int row = L >> 8;
    int srb = (L & 255) ^ ((row & 7) << 4);
    char* d = sL + 65536 + it * 8192 + wave * 1024;
    gload_lds16((const char*)Ws2T + row * 256 + srb, d);
    gload_lds16((const char*)Wn2T + row * 256 + srb, d + 16384);
  }
  int tt = blockIdx.x;
  if (tt < NT_TILES) stage_tile(xb, aggb, tt, sL + 98304, tid, wave, N);

  // ---- biases: loop-invariant plain loads (hoisted; once per block) ----
  float4 bv1[4], bv2[4];
#pragma unroll
  for (int ft = 0; ft < 4; ++ft) {
    bv1[ft] = *(const float4*)(b1 + fbase + ft * 16 + q * 4);
    bv2[ft] = *(const float4*)(b2 + ft * 16 + q * 4);
  }

  // ---- persistent tile loop ----
  int li = 0;
  for (; tt < NT_TILES; tt += GEMM_GRID, ++li) {
    char* cur = sL + 98304 + (li & 1) * 32768;
    char* nxt = sL + 98304 + ((li + 1) & 1) * 32768;

    __syncthreads();  // B1: vmcnt(0) drain -> DMA(cur) complete; prev phase-2 LDS reads done

    if (tt + GEMM_GRID < NT_TILES)           // prefetch next tile (stays in flight across
      stage_tile(xb, aggb, tt + GEMM_GRID, nxt, tid, wave, N);  // the raw barriers below)

    // ---- phase 1: h1 = relu(x@Ws1 + agg@Wn1 + b1), operands all from LDS ----
    frag_cd acc[4];
#pragma unroll
    for (int ft = 0; ft < 4; ++ft) acc[ft] = (frag_cd)(0.f);

    const int xrow = nodeq * 16 + l15;
    const int xswz = (xrow & 7) << 4;
#pragma unroll
    for (int kb = 0; kb < 4; ++kb) {
      int base = kb * 64 + q * 16;
      frag_ab axk = *(const frag_ab*)(cur + xrow * 256 + (base ^ xswz));
      frag_ab agk = *(const frag_ab*)(cur + 16384 + xrow * 256 + (base ^ xswz));
      frag_ab fs[4], fn[4];
#pragma unroll
      for (int ft = 0; ft < 4; ++ft) {
        int wrow = fbase + ft * 16 + l15;
        int woff = base ^ ((wrow & 7) << 4);
        fs[ft] = *(const frag_ab*)(sL + wrow * 256 + woff);
        fn[ft] = *(const frag_ab*)(sL + 32768 + wrow * 256 + woff);
      }
#pragma unroll
      for (int ft = 0; ft < 4; ++ft) {
        acc[ft] = __builtin_amdgcn_mfma_f32_16x16x32_bf16(fs[ft], axk, acc[ft], 0, 0, 0);
        acc[ft] = __builtin_amdgcn_mfma_f32_16x16x32_bf16(fn[ft], agk, acc[ft], 0, 0, 0);
      }
    }

    lgkm_barrier();  // B2: all phase-1 x reads done before h1 overwrites (DMA stays in flight)

    // epilogue 1: relu(acc + b1) -> h1 (cur x region, same swizzle)
#pragma unroll
    for (int ft = 0; ft < 4; ++ft) {
      int f0 = fbase + ft * 16 + q * 4;
      ushort4 o;
      o.x = f2b(fmaxf(acc[ft][0] + bv1[ft].x, 0.f));
      o.y = f2b(fmaxf(acc[ft][1] + bv1[ft].y, 0.f));
      o.z = f2b(fmaxf(acc[ft][2] + bv1[ft].z, 0.f));
      o.w = f2b(fmaxf(acc[ft][3] + bv1[ft].w, 0.f));
      *(ushort4*)(cur + xrow * 256 + ((f0 * 2) ^ xswz)) = o;
    }

    lgkm_barrier();  // B3: h1 visible to all waves (DMA still in flight)

    // ---- phase 2: out = h1@Ws2 + b2 (fhalf 0), g = h1@Wn2 (fhalf 1) ----
    const char* w2b = sL + 65536 + fhalf * 16384;
    frag_cd acc2[4];
#pragma unroll
    for (int ft = 0; ft < 4; ++ft) acc2[ft] = (frag_cd)(0.f);

#pragma unroll
    for (int kb = 0; kb < 4; ++kb) {
      int base = kb * 64 + q * 16;
      frag_ab ah = *(const frag_ab*)(cur + xrow * 256 + (base ^ xswz));
      frag_ab w2[4];
#pragma unroll
      for (int ft = 0; ft < 4; ++ft) {
        int wr = ft * 16 + l15;
        w2[ft] = *(const frag_ab*)(w2b + wr * 256 + (base ^ ((wr & 7) << 4)));
      }
#pragma unroll
      for (int ft = 0; ft < 4; ++ft)
        acc2[ft] = __builtin_amdgcn_mfma_f32_16x16x32_bf16(w2[ft], ah, acc2[ft], 0, 0, 0);
    }

    int node = tt * 64 + nodeq * 16 + l15;
    if (node < N) {
      if (fhalf == 0) {
#pragma unroll
        for (int ft = 0; ft < 4; ++ft) {
          int f0 = ft * 16 + q * 4;
          float4 o;
          o.x = acc2[ft][0] + bv2[ft].x;
          o.y = acc2[ft][1] + bv2[ft].y;
          o.z = acc2[ft][2] + bv2[ft].z;
          o.w = acc2[ft][3] + bv2[ft].w;
          *(float4*)(out + (size_t)node * M2 + f0) = o;
        }
      } else {
#pragma unroll
        for (int ft = 0; ft < 4; ++ft) {
          int f0 = ft * 16 + q * 4;
          ushort4 o;
          o.x = f2b(acc2[ft][0]);
          o.y = f2b(acc2[ft][1]);
          o.z = f2b(acc2[ft][2]);
          o.w = f2b(acc2[ft][3]);
          *(ushort4*)(g + (size_t)node * M2 + f0) = o;
        }
      }
    }
  }
}

extern "C" void kernel_launch(void* const* d_in, const int* in_sizes, int n_in,
                              void* d_out, int out_size, void* d_ws, size_t ws_size,
                              hipStream_t stream) {
  const float* x   = (const float*)d_in[0];
  const int*   src = (const int*)d_in[1];
  const int*   dst = (const int*)d_in[2];
  const float* Ws1 = (const float*)d_in[3];
  const float* Wn1 = (const float*)d_in[4];
  const float* b1  = (const float*)d_in[5];
  const float* Ws2 = (const float*)d_in[6];
  const float* Wn2 = (const float*)d_in[7];
  const float* b2  = (const float*)d_in[8];
  float* out = (float*)d_out;

  char* ws = (char*)d_ws;
  size_t off = 0;
  auto alloc = [&](size_t bytes) {
    void* p = ws + off;
    off = (off + bytes + 4095) & ~(size_t)4095;
    return p;
  };
  int* deg       = (int*)alloc((size_t)N_NODES * 4);
  int* row_ptr   = (int*)alloc((size_t)(N_NODES + 1) * 4);
  int* cursor    = (int*)alloc((size_t)N_NODES * 4);
  int* blockSums = (int*)alloc(512 * 4);
  int* csr_src   = (int*)alloc((size_t)N_EDGES * 4);
  unsigned short* xb   = (unsigned short*)alloc((size_t)N_NODES * K_DIM * 2);
  unsigned short* aggb = (unsigned short*)alloc((size_t)N_NODES * K_DIM * 2);
  unsigned short* g    = (unsigned short*)alloc((size_t)N_NODES * M2 * 2);
  unsigned short* Ws1T = (unsigned short*)alloc((size_t)128 * 128 * 2);
  unsigned short* Wn1T = (unsigned short*)alloc((size_t)128 * 128 * 2);
  unsigned short* Ws2T = (unsigned short*)alloc((size_t)64 * 128 * 2);
  unsigned short* Wn2T = (unsigned short*)alloc((size_t)64 * 128 * 2);

  hipMemsetAsync(deg, 0, (size_t)N_NODES * 4, stream);

  // fused conversions (x -> bf16, weight transposes) + degree count
  conv_all<<<XB_BLOCKS + WB_BLOCKS + DEG_BLOCKS, 256, 0, stream>>>(
      x, xb, Ws1, Wn1, Ws2, Wn2, Ws1T, Wn1T, Ws2T, Wn2T, dst, deg);

  // CSR build: 2-stage scan -> fill
  scan1<<<SCAN_BLOCKS, 256, 0, stream>>>(deg, row_ptr, blockSums, N_NODES);
  scanB<<<(N_NODES + 511) / 512, 512, 0, stream>>>(row_ptr, blockSums, cursor, N_NODES, N_EDGES);
  csr_fill<<<(N_EDGES + 255) / 256, 256, 0, stream>>>(src, dst, cursor, csr_src, N_EDGES);

  // layer-1 aggregation (gather-mean, 8-wide predicated batches)
  {
    long t = (long)N_NODES * 16;
    aggregate128<<<(int)((t + 255) / 256), 256, 0, stream>>>(xb, row_ptr, csr_src, aggb, N_NODES);
  }

  // fused layer-1 + layer-2 GEMMs: persistent blocks, weights staged once, tile-ahead DMA
  sage_fused_gemm<<<GEMM_GRID, 512, 0, stream>>>(
      xb, aggb, Ws1T, Wn1T, b1, Ws2T, Wn2T, b2, out, g, N_NODES);

  // layer-2 aggregation (adds mean(g) into out)
  {
    long t = (long)N_NODES * 8;
    aggregate64_add<<<(int)((t + 255) / 256), 256, 0, stream>>>(g, row_ptr, csr_src, out, N_NODES);
  }
}

// Round 7
// 223.622 us; speedup vs baseline: 1.1550x; 1.0779x over previous
//
#include <hip/hip_runtime.h>

#define N_NODES 100000
#define N_EDGES 600000
#define K_DIM 128
#define M2 64
#define SCAN_BLOCKS ((N_NODES + 255) / 256)   // 391
#define NT_TILES ((N_NODES + 63) / 64)        // 1563 64-node tiles
#define GEMM_GRID 256

using frag_ab = __attribute__((ext_vector_type(8))) short;   // 8 bf16 = 4 VGPRs
using frag_cd = __attribute__((ext_vector_type(4))) float;   // 4 fp32 acc

// fp32 -> bf16 round-to-nearest-even
__device__ __forceinline__ unsigned short f2b(float f) {
  unsigned u = __builtin_bit_cast(unsigned, f);
  u = (u + 0x7fffu + ((u >> 16) & 1u)) >> 16;
  return (unsigned short)u;
}

// async global->LDS, 16 B per lane. LDS dest wave-uniform (HW adds lane*16);
// global src per-lane (swizzled LDS layouts = pre-swizzle the source).
__device__ __forceinline__ void gload_lds16(const void* gsrc, void* ldst) {
  __builtin_amdgcn_global_load_lds(
      (const __attribute__((address_space(1))) void*)gsrc,
      (__attribute__((address_space(3))) void*)ldst, 16, 0, 0);
}

// raw barrier: drain LDS ops only, keep DMA/stores (vmcnt) in flight
__device__ __forceinline__ void lgkm_barrier() {
  __builtin_amdgcn_sched_barrier(0);
  asm volatile("s_waitcnt lgkmcnt(0)" ::: "memory");
  __builtin_amdgcn_s_barrier();
  __builtin_amdgcn_sched_barrier(0);
}

// ---------------- fused: x->bf16 conversion + 4 weight transposes + degree+pos count ----------------
// v6: the degree atomic now RETURNS each edge's intra-row slot (pos[e]), making csr_fill
// atomic-free. Same 600K atomics as before; the 600K cursor atomics in csr_fill vanish.
#define XB_BLOCKS ((N_NODES * K_DIM / 4 + 255) / 256)            // 12500
#define W_ELEMS ((128 + 128 + 64 + 64) * 128)                    // 49152
#define WB_BLOCKS ((W_ELEMS + 255) / 256)                        // 192
#define DEG_BLOCKS ((N_EDGES + 255) / 256)                       // 2344
__global__ __launch_bounds__(256) void conv_all(const float* __restrict__ x,
                                                unsigned short* __restrict__ xb,
                                                const float* __restrict__ Ws1,
                                                const float* __restrict__ Wn1,
                                                const float* __restrict__ Ws2,
                                                const float* __restrict__ Wn2,
                                                unsigned short* __restrict__ Ws1T,
                                                unsigned short* __restrict__ Wn1T,
                                                unsigned short* __restrict__ Ws2T,
                                                unsigned short* __restrict__ Wn2T,
                                                const int* __restrict__ dst,
                                                int* __restrict__ deg,
                                                int* __restrict__ pos) {
  if (blockIdx.x < XB_BLOCKS) {
    long i = (long)blockIdx.x * 256 + threadIdx.x;
    if (i >= (long)N_NODES * K_DIM / 4) return;
    float4 v = *(const float4*)(x + i * 4);
    ushort4 o;
    o.x = f2b(v.x); o.y = f2b(v.y); o.z = f2b(v.z); o.w = f2b(v.w);
    *(ushort4*)(xb + i * 4) = o;
  } else if (blockIdx.x < XB_BLOCKS + WB_BLOCKS) {
    int i = (blockIdx.x - XB_BLOCKS) * 256 + threadIdx.x;  // global weight elem
    if (i >= W_ELEMS) return;
    const float* W;
    unsigned short* WT;
    int M, li;
    if (i < 128 * 128)               { W = Ws1; WT = Ws1T; M = 128; li = i; }
    else if (i < 2 * 128 * 128)      { W = Wn1; WT = Wn1T; M = 128; li = i - 128 * 128; }
    else if (i < 2 * 128 * 128 + 64 * 128) { W = Ws2; WT = Ws2T; M = 64; li = i - 2 * 128 * 128; }
    else                             { W = Wn2; WT = Wn2T; M = 64; li = i - 2 * 128 * 128 - 64 * 128; }
    int n = li >> 7, k = li & 127;   // li = n*128 + k
    WT[li] = f2b(W[k * M + n]);
  } else {
    int e = (blockIdx.x - XB_BLOCKS - WB_BLOCKS) * 256 + threadIdx.x;
    if (e < N_EDGES) pos[e] = atomicAdd(&deg[dst[e]], 1);
  }
}

// ---------------- scan stage 1: per-256-block exclusive partials + block sums ----------------
__global__ __launch_bounds__(256) void scan1(const int* __restrict__ deg,
                                             int* __restrict__ partial,
                                             int* __restrict__ blockSums, int n) {
  __shared__ int sdata[256];
  int tid = threadIdx.x;
  int i = blockIdx.x * 256 + tid;
  int v = (i < n) ? deg[i] : 0;
  sdata[tid] = v;
  __syncthreads();
#pragma unroll
  for (int off = 1; off < 256; off <<= 1) {
    int t = (tid >= off) ? sdata[tid - off] : 0;
    __syncthreads();
    sdata[tid] += t;
    __syncthreads();
  }
  if (i < n) partial[i] = sdata[tid] - v;
  if (tid == 255) blockSums[blockIdx.x] = sdata[255];
}

// ---------------- scan stage 2: every block redundantly scans blockSums, finalizes slice ----------------
__global__ __launch_bounds__(512) void scanB(int* __restrict__ row_ptr,   // partial in, full out
                                             const int* __restrict__ blockSums,
                                             int n, int nE) {
  __shared__ int bs[512];
  int tid = threadIdx.x;
  int v = (tid < SCAN_BLOCKS) ? blockSums[tid] : 0;
  bs[tid] = v;
  __syncthreads();
#pragma unroll
  for (int off = 1; off < 512; off <<= 1) {
    int t = (tid >= off) ? bs[tid - off] : 0;
    __syncthreads();
    bs[tid] += t;
    __syncthreads();
  }
  bs[tid] -= v;
  __syncthreads();

  int i = blockIdx.x * 512 + tid;
  if (i < n) row_ptr[i] += bs[i >> 8];
  if (i == 0) row_ptr[n] = nE;
}

// ---------------- CSR fill (v6: atomic-free — slot precomputed in pos[]) ----------------
__global__ __launch_bounds__(256) void csr_fill(const int* __restrict__ src,
                                                const int* __restrict__ dst,
                                                const int* __restrict__ row_ptr,
                                                const int* __restrict__ pos,
                                                int* __restrict__ csr_src, int nE) {
  int e = blockIdx.x * blockDim.x + threadIdx.x;
  if (e < nE) csr_src[row_ptr[dst[e]] + pos[e]] = src[e];
}

// ---------------- gather-mean, 128 bf16 cols: 16 threads/node, 8-wide predicated batches ----------------
__global__ __launch_bounds__(256) void aggregate128(const unsigned short* __restrict__ xb,
                                                    const int* __restrict__ row_ptr,
                                                    const int* __restrict__ csr_src,
                                                    unsigned short* __restrict__ agg, int n) {
  int t = blockIdx.x * blockDim.x + threadIdx.x;
  int node = t >> 4;
  int c = (t & 15) << 3;  // 8 bf16 per thread
  if (node >= n) return;
  int beg = row_ptr[node], end = row_ptr[node + 1];
  float acc[8];
#pragma unroll
  for (int j = 0; j < 8; ++j) acc[j] = 0.f;

  if (end > beg) {
    for (int e0 = beg; e0 < end; e0 += 8) {
      int idx[8];
#pragma unroll
      for (int p = 0; p < 8; ++p) idx[p] = csr_src[min(e0 + p, end - 1)];
      uint4 v[8];
#pragma unroll
      for (int p = 0; p < 8; ++p) v[p] = *(const uint4*)(xb + (size_t)idx[p] * K_DIM + c);
#pragma unroll
      for (int p = 0; p < 8; ++p) {
        float m = (e0 + p < end) ? 1.f : 0.f;
        unsigned u[4] = {v[p].x, v[p].y, v[p].z, v[p].w};
#pragma unroll
        for (int j = 0; j < 4; ++j) {
          acc[2 * j]     += m * __builtin_bit_cast(float, u[j] << 16);
          acc[2 * j + 1] += m * __builtin_bit_cast(float, u[j] & 0xffff0000u);
        }
      }
    }
  }
  float inv = 1.0f / (float)max(end - beg, 1);
  uint4 o;
  unsigned* op = (unsigned*)&o;
#pragma unroll
  for (int j = 0; j < 4; ++j) {
    unsigned lo = f2b(acc[2 * j] * inv);
    unsigned hi = f2b(acc[2 * j + 1] * inv);
    op[j] = lo | (hi << 16);
  }
  *(uint4*)(agg + (size_t)node * K_DIM + c) = o;
}

// ---------------- gather-mean-add, 64 bf16 cols -> out fp32: 8 threads/node, 8-wide batches ----------------
__global__ __launch_bounds__(256) void aggregate64_add(const unsigned short* __restrict__ g,
                                                       const int* __restrict__ row_ptr,
                                                       const int* __restrict__ csr_src,
                                                       float* __restrict__ out, int n) {
  int t = blockIdx.x * blockDim.x + threadIdx.x;
  int node = t >> 3;
  int c = (t & 7) << 3;  // 8 bf16 per thread
  if (node >= n) return;
  int beg = row_ptr[node], end = row_ptr[node + 1];
  float acc[8];
#pragma unroll
  for (int j = 0; j < 8; ++j) acc[j] = 0.f;

  if (end > beg) {
    for (int e0 = beg; e0 < end; e0 += 8) {
      int idx[8];
#pragma unroll
      for (int p = 0; p < 8; ++p) idx[p] = csr_src[min(e0 + p, end - 1)];
      uint4 v[8];
#pragma unroll
      for (int p = 0; p < 8; ++p) v[p] = *(const uint4*)(g + (size_t)idx[p] * M2 + c);
#pragma unroll
      for (int p = 0; p < 8; ++p) {
        float m = (e0 + p < end) ? 1.f : 0.f;
        unsigned u[4] = {v[p].x, v[p].y, v[p].z, v[p].w};
#pragma unroll
        for (int j = 0; j < 4; ++j) {
          acc[2 * j]     += m * __builtin_bit_cast(float, u[j] << 16);
          acc[2 * j + 1] += m * __builtin_bit_cast(float, u[j] & 0xffff0000u);
        }
      }
    }
  }
  float inv = 1.0f / (float)max(end - beg, 1);
  float* op = out + (size_t)node * M2 + c;
  float4 o0 = *(float4*)(op);
  float4 o1 = *(float4*)(op + 4);
  o0.x += acc[0] * inv; o0.y += acc[1] * inv; o0.z += acc[2] * inv; o0.w += acc[3] * inv;
  o1.x += acc[4] * inv; o1.y += acc[5] * inv; o1.z += acc[6] * inv; o1.w += acc[7] * inv;
  *(float4*)(op) = o0;
  *(float4*)(op + 4) = o1;
}

// stage one 64-node tile of x+agg (32 KB) into LDS dbuf half, swizzled source
__device__ __forceinline__ void stage_tile(const unsigned short* xb, const unsigned short* aggb,
                                           int t, char* dstbase, int tid, int wave, int N) {
#pragma unroll
  for (int it = 0; it < 2; ++it) {
    int L = it * 8192 + tid * 16;            // [0, 16384)
    int row = L >> 8;                        // 0..63
    int srb = (L & 255) ^ ((row & 7) << 4);  // inverse-swizzled source byte
    int node = t * 64 + row;
    if (node >= N) node = N - 1;             // clamp (garbage rows never stored)
    char* d = dstbase + it * 8192 + wave * 1024;  // wave-uniform; HW adds lane*16
    gload_lds16((const char*)xb + (size_t)node * 256 + srb, d);
    gload_lds16((const char*)aggb + (size_t)node * 256 + srb, d + 16384);
  }
}

// ---------------- fused both-layer GEMM (v5: persistent, everything via DMA+LDS) ----------------
// Confirmed working (round 6): fell below the 40.5us top-5 cutoff from 45.5us.
// Rule distilled from v1-v4: any global->VGPR operand load feeding MFMA gets latency-
// serialized by the compiler; global_load_lds is the only reliably-batched path.
// Persistent blocks (grid=256, 1/CU, 512 thr), weights staged ONCE (W1 64K + W2 32K),
// x/agg 2x32K double-buffer with one-tile-ahead DMA; raw lgkm-only barriers keep the
// prefetch DMA in flight; the per-iteration __syncthreads is the single vmcnt drain.
// LDS = 160KB. h1 overlays the consumed x region. XOR swizzle (byte^=(row&7)<<4).
__global__ __launch_bounds__(512, 2) void sage_fused_gemm(const unsigned short* __restrict__ xb,
                                                          const unsigned short* __restrict__ aggb,
                                                          const unsigned short* __restrict__ Ws1T,
                                                          const unsigned short* __restrict__ Wn1T,
                                                          const float* __restrict__ b1,
                                                          const unsigned short* __restrict__ Ws2T,
                                                          const unsigned short* __restrict__ Wn2T,
                                                          const float* __restrict__ b2,
                                                          float* __restrict__ out,
                                                          unsigned short* __restrict__ g, int N) {
  // [0,32K) Ws1T | [32K,64K) Wn1T | [64K,80K) Ws2T | [80K,96K) Wn2T | [96K,128K) buf0 | [128K,160K) buf1
  __shared__ char sL[163840];

  const int tid = threadIdx.x;
  const int wave = tid >> 6;
  const int lane = tid & 63;
  const int l15 = lane & 15;
  const int q = lane >> 4;
  const int nodeq = wave >> 1;     // 0..3 -> 16-node strip
  const int fhalf = wave & 1;      // phase-1 feat half / phase-2 output matrix
  const int fbase = fhalf * 64;

  // ---- prologue: stage all weights (96 KB) + first tile (once per block) ----
#pragma unroll
  for (int it = 0; it < 4; ++it) {           // W1: 2 x 32K
    int L = it * 8192 + tid * 16;
    int row = L >> 8;
    int srb = (L & 255) ^ ((row & 7) << 4);
    char* d = sL + it * 8192 + wave * 1024;
    gload_lds16((const char*)Ws1T + row * 256 + srb, d);
    gload_lds16((const char*)Wn1T + row * 256 + srb, d + 32768);
  }
#pragma unroll
  for (int it = 0; it < 2; ++it) {           // W2: 2 x 16K
    int L = it * 8192 + tid * 16;
    int row = L >> 8;
    int srb = (L & 255) ^ ((row & 7) << 4);
    char* d = sL + 65536 + it * 8192 + wave * 1024;
    gload_lds16((const char*)Ws2T + row * 256 + srb, d);
    gload_lds16((const char*)Wn2T + row * 256 + srb, d + 16384);
  }
  int tt = blockIdx.x;
  if (tt < NT_TILES) stage_tile(xb, aggb, tt, sL + 98304, tid, wave, N);

  // ---- biases: loop-invariant plain loads (hoisted; once per block) ----
  float4 bv1[4], bv2[4];
#pragma unroll
  for (int ft = 0; ft < 4; ++ft) {
    bv1[ft] = *(const float4*)(b1 + fbase + ft * 16 + q * 4);
    bv2[ft] = *(const float4*)(b2 + ft * 16 + q * 4);
  }

  // ---- persistent tile loop ----
  int li = 0;
  for (; tt < NT_TILES; tt += GEMM_GRID, ++li) {
    char* cur = sL + 98304 + (li & 1) * 32768;
    char* nxt = sL + 98304 + ((li + 1) & 1) * 32768;

    __syncthreads();  // B1: vmcnt(0) drain -> DMA(cur) complete; prev phase-2 LDS reads done

    if (tt + GEMM_GRID < NT_TILES)           // prefetch next tile (stays in flight across
      stage_tile(xb, aggb, tt + GEMM_GRID, nxt, tid, wave, N);  // the raw barriers below)

    // ---- phase 1: h1 = relu(x@Ws1 + agg@Wn1 + b1), operands all from LDS ----
    frag_cd acc[4];
#pragma unroll
    for (int ft = 0; ft < 4; ++ft) acc[ft] = (frag_cd)(0.f);

    const int xrow = nodeq * 16 + l15;
    const int xswz = (xrow & 7) << 4;
#pragma unroll
    for (int kb = 0; kb < 4; ++kb) {
      int base = kb * 64 + q * 16;
      frag_ab axk = *(const frag_ab*)(cur + xrow * 256 + (base ^ xswz));
      frag_ab agk = *(const frag_ab*)(cur + 16384 + xrow * 256 + (base ^ xswz));
      frag_ab fs[4], fn[4];
#pragma unroll
      for (int ft = 0; ft < 4; ++ft) {
        int wrow = fbase + ft * 16 + l15;
        int woff = base ^ ((wrow & 7) << 4);
        fs[ft] = *(const frag_ab*)(sL + wrow * 256 + woff);
        fn[ft] = *(const frag_ab*)(sL + 32768 + wrow * 256 + woff);
      }
#pragma unroll
      for (int ft = 0; ft < 4; ++ft) {
        acc[ft] = __builtin_amdgcn_mfma_f32_16x16x32_bf16(fs[ft], axk, acc[ft], 0, 0, 0);
        acc[ft] = __builtin_amdgcn_mfma_f32_16x16x32_bf16(fn[ft], agk, acc[ft], 0, 0, 0);
      }
    }

    lgkm_barrier();  // B2: all phase-1 x reads done before h1 overwrites (DMA stays in flight)

    // epilogue 1: relu(acc + b1) -> h1 (cur x region, same swizzle)
#pragma unroll
    for (int ft = 0; ft < 4; ++ft) {
      int f0 = fbase + ft * 16 + q * 4;
      ushort4 o;
      o.x = f2b(fmaxf(acc[ft][0] + bv1[ft].x, 0.f));
      o.y = f2b(fmaxf(acc[ft][1] + bv1[ft].y, 0.f));
      o.z = f2b(fmaxf(acc[ft][2] + bv1[ft].z, 0.f));
      o.w = f2b(fmaxf(acc[ft][3] + bv1[ft].w, 0.f));
      *(ushort4*)(cur + xrow * 256 + ((f0 * 2) ^ xswz)) = o;
    }

    lgkm_barrier();  // B3: h1 visible to all waves (DMA still in flight)

    // ---- phase 2: out = h1@Ws2 + b2 (fhalf 0), g = h1@Wn2 (fhalf 1) ----
    const char* w2b = sL + 65536 + fhalf * 16384;
    frag_cd acc2[4];
#pragma unroll
    for (int ft = 0; ft < 4; ++ft) acc2[ft] = (frag_cd)(0.f);

#pragma unroll
    for (int kb = 0; kb < 4; ++kb) {
      int base = kb * 64 + q * 16;
      frag_ab ah = *(const frag_ab*)(cur + xrow * 256 + (base ^ xswz));
      frag_ab w2[4];
#pragma unroll
      for (int ft = 0; ft < 4; ++ft) {
        int wr = ft * 16 + l15;
        w2[ft] = *(const frag_ab*)(w2b + wr * 256 + (base ^ ((wr & 7) << 4)));
      }
#pragma unroll
      for (int ft = 0; ft < 4; ++ft)
        acc2[ft] = __builtin_amdgcn_mfma_f32_16x16x32_bf16(w2[ft], ah, acc2[ft], 0, 0, 0);
    }

    int node = tt * 64 + nodeq * 16 + l15;
    if (node < N) {
      if (fhalf == 0) {
#pragma unroll
        for (int ft = 0; ft < 4; ++ft) {
          int f0 = ft * 16 + q * 4;
          float4 o;
          o.x = acc2[ft][0] + bv2[ft].x;
          o.y = acc2[ft][1] + bv2[ft].y;
          o.z = acc2[ft][2] + bv2[ft].z;
          o.w = acc2[ft][3] + bv2[ft].w;
          *(float4*)(out + (size_t)node * M2 + f0) = o;
        }
      } else {
#pragma unroll
        for (int ft = 0; ft < 4; ++ft) {
          int f0 = ft * 16 + q * 4;
          ushort4 o;
          o.x = f2b(acc2[ft][0]);
          o.y = f2b(acc2[ft][1]);
          o.z = f2b(acc2[ft][2]);
          o.w = f2b(acc2[ft][3]);
          *(ushort4*)(g + (size_t)node * M2 + f0) = o;
        }
      }
    }
  }
}

extern "C" void kernel_launch(void* const* d_in, const int* in_sizes, int n_in,
                              void* d_out, int out_size, void* d_ws, size_t ws_size,
                              hipStream_t stream) {
  const float* x   = (const float*)d_in[0];
  const int*   src = (const int*)d_in[1];
  const int*   dst = (const int*)d_in[2];
  const float* Ws1 = (const float*)d_in[3];
  const float* Wn1 = (const float*)d_in[4];
  const float* b1  = (const float*)d_in[5];
  const float* Ws2 = (const float*)d_in[6];
  const float* Wn2 = (const float*)d_in[7];
  const float* b2  = (const float*)d_in[8];
  float* out = (float*)d_out;

  char* ws = (char*)d_ws;
  size_t off = 0;
  auto alloc = [&](size_t bytes) {
    void* p = ws + off;
    off = (off + bytes + 4095) & ~(size_t)4095;
    return p;
  };
  int* deg       = (int*)alloc((size_t)N_NODES * 4);
  int* row_ptr   = (int*)alloc((size_t)(N_NODES + 1) * 4);
  int* pos       = (int*)alloc((size_t)N_EDGES * 4);
  int* blockSums = (int*)alloc(512 * 4);
  int* csr_src   = (int*)alloc((size_t)N_EDGES * 4);
  unsigned short* xb   = (unsigned short*)alloc((size_t)N_NODES * K_DIM * 2);
  unsigned short* aggb = (unsigned short*)alloc((size_t)N_NODES * K_DIM * 2);
  unsigned short* g    = (unsigned short*)alloc((size_t)N_NODES * M2 * 2);
  unsigned short* Ws1T = (unsigned short*)alloc((size_t)128 * 128 * 2);
  unsigned short* Wn1T = (unsigned short*)alloc((size_t)128 * 128 * 2);
  unsigned short* Ws2T = (unsigned short*)alloc((size_t)64 * 128 * 2);
  unsigned short* Wn2T = (unsigned short*)alloc((size_t)64 * 128 * 2);

  hipMemsetAsync(deg, 0, (size_t)N_NODES * 4, stream);

  // fused conversions (x -> bf16, weight transposes) + degree count with slot capture
  conv_all<<<XB_BLOCKS + WB_BLOCKS + DEG_BLOCKS, 256, 0, stream>>>(
      x, xb, Ws1, Wn1, Ws2, Wn2, Ws1T, Wn1T, Ws2T, Wn2T, dst, deg, pos);

  // CSR build: 2-stage scan -> atomic-free fill
  scan1<<<SCAN_BLOCKS, 256, 0, stream>>>(deg, row_ptr, blockSums, N_NODES);
  scanB<<<(N_NODES + 511) / 512, 512, 0, stream>>>(row_ptr, blockSums, N_NODES, N_EDGES);
  csr_fill<<<(N_EDGES + 255) / 256, 256, 0, stream>>>(src, dst, row_ptr, pos, csr_src, N_EDGES);

  // layer-1 aggregation (gather-mean, 8-wide predicated batches)
  {
    long t = (long)N_NODES * 16;
    aggregate128<<<(int)((t + 255) / 256), 256, 0, stream>>>(xb, row_ptr, csr_src, aggb, N_NODES);
  }

  // fused layer-1 + layer-2 GEMMs: persistent blocks, weights staged once, tile-ahead DMA
  sage_fused_gemm<<<GEMM_GRID, 512, 0, stream>>>(
      xb, aggb, Ws1T, Wn1T, b1, Ws2T, Wn2T, b2, out, g, N_NODES);

  // layer-2 aggregation (adds mean(g) into out)
  {
    long t = (long)N_NODES * 8;
    aggregate64_add<<<(int)((t + 255) / 256), 256, 0, stream>>>(g, row_ptr, csr_src, out, N_NODES);
  }
}

// Round 8
// 209.885 us; speedup vs baseline: 1.2306x; 1.0654x over previous
//
#include <hip/hip_runtime.h>

#define N_NODES 100000
#define N_EDGES 600000
#define K_DIM 128
#define M2 64
#define NT_TILES ((N_NODES + 63) / 64)        // 1563 64-node tiles
#define GEMM_GRID 256

// two-level CSR build
#define NBKT 800                              // buckets
#define NPB 125                               // nodes per bucket (800*125 = 100000)
#define HIST_BLOCKS 64
#define EPB (N_EDGES / HIST_BLOCKS)           // 9375 edges per hist block

using frag_ab = __attribute__((ext_vector_type(8))) short;   // 8 bf16 = 4 VGPRs
using frag_cd = __attribute__((ext_vector_type(4))) float;   // 4 fp32 acc

// fp32 -> bf16 round-to-nearest-even
__device__ __forceinline__ unsigned short f2b(float f) {
  unsigned u = __builtin_bit_cast(unsigned, f);
  u = (u + 0x7fffu + ((u >> 16) & 1u)) >> 16;
  return (unsigned short)u;
}

// async global->LDS, 16 B per lane. LDS dest wave-uniform (HW adds lane*16);
// global src per-lane (swizzled LDS layouts = pre-swizzle the source).
__device__ __forceinline__ void gload_lds16(const void* gsrc, void* ldst) {
  __builtin_amdgcn_global_load_lds(
      (const __attribute__((address_space(1))) void*)gsrc,
      (__attribute__((address_space(3))) void*)ldst, 16, 0, 0);
}

// raw barrier: drain LDS ops only, keep DMA/stores (vmcnt) in flight
__device__ __forceinline__ void lgkm_barrier() {
  __builtin_amdgcn_sched_barrier(0);
  asm volatile("s_waitcnt lgkmcnt(0)" ::: "memory");
  __builtin_amdgcn_s_barrier();
  __builtin_amdgcn_sched_barrier(0);
}

// ---------------- fused: bucket-hist (overlaps streaming) + x->bf16 + weight transposes ----------------
// v7: flat 600K global-atomic degree count replaced by two-level bucket scheme.
// Section 1 (blocks 0..63): per-block LDS histogram over 800 buckets with pos capture,
// then <=800 global atomics/block to reserve per-(block,bucket) bases -> 51K global atomics.
#define XB_BLOCKS ((N_NODES * K_DIM / 4 + 255) / 256)            // 12500
#define W_ELEMS ((128 + 128 + 64 + 64) * 128)                    // 49152
#define WB_BLOCKS ((W_ELEMS + 255) / 256)                        // 192
__global__ __launch_bounds__(256) void conv_all(const float* __restrict__ x,
                                                unsigned short* __restrict__ xb,
                                                const float* __restrict__ Ws1,
                                                const float* __restrict__ Wn1,
                                                const float* __restrict__ Ws2,
                                                const float* __restrict__ Wn2,
                                                unsigned short* __restrict__ Ws1T,
                                                unsigned short* __restrict__ Wn1T,
                                                unsigned short* __restrict__ Ws2T,
                                                unsigned short* __restrict__ Wn2T,
                                                const int* __restrict__ dst,
                                                int* __restrict__ pos,
                                                int* __restrict__ gbucket,
                                                int* __restrict__ base_tbl) {
  __shared__ int lcnt[NBKT];
  if (blockIdx.x < HIST_BLOCKS) {
    int tid = threadIdx.x;
    for (int i = tid; i < NBKT; i += 256) lcnt[i] = 0;
    __syncthreads();
    int e0 = blockIdx.x * EPB;
    for (int e = e0 + tid; e < e0 + EPB; e += 256) {
      int b = dst[e] / NPB;
      pos[e] = atomicAdd(&lcnt[b], 1);     // LDS atomic with capture
    }
    __syncthreads();
    for (int i = tid; i < NBKT; i += 256) {
      int c = lcnt[i];
      if (c) base_tbl[blockIdx.x * NBKT + i] = atomicAdd(&gbucket[i], c);
    }
  } else if (blockIdx.x < HIST_BLOCKS + XB_BLOCKS) {
    long i = (long)(blockIdx.x - HIST_BLOCKS) * 256 + threadIdx.x;
    if (i >= (long)N_NODES * K_DIM / 4) return;
    float4 v = *(const float4*)(x + i * 4);
    ushort4 o;
    o.x = f2b(v.x); o.y = f2b(v.y); o.z = f2b(v.z); o.w = f2b(v.w);
    *(ushort4*)(xb + i * 4) = o;
  } else {
    int i = (blockIdx.x - HIST_BLOCKS - XB_BLOCKS) * 256 + threadIdx.x;
    if (i >= W_ELEMS) return;
    const float* W;
    unsigned short* WT;
    int M, li;
    if (i < 128 * 128)               { W = Ws1; WT = Ws1T; M = 128; li = i; }
    else if (i < 2 * 128 * 128)      { W = Wn1; WT = Wn1T; M = 128; li = i - 128 * 128; }
    else if (i < 2 * 128 * 128 + 64 * 128) { W = Ws2; WT = Ws2T; M = 64; li = i - 2 * 128 * 128; }
    else                             { W = Wn2; WT = Wn2T; M = 64; li = i - 2 * 128 * 128 - 64 * 128; }
    int n = li >> 7, k = li & 127;   // li = n*128 + k
    WT[li] = f2b(W[k * M + n]);
  }
}

// ---------------- exclusive scan of 800 bucket totals (replaces scan1+scanB) ----------------
__global__ __launch_bounds__(1024) void scan_buckets(const int* __restrict__ gbucket,
                                                     int* __restrict__ bucket_start,
                                                     int* __restrict__ row_ptr) {
  __shared__ int s[1024];
  int tid = threadIdx.x;
  int v = (tid < NBKT) ? gbucket[tid] : 0;
  s[tid] = v;
  __syncthreads();
  for (int off = 1; off < 1024; off <<= 1) {
    int t = (tid >= off) ? s[tid - off] : 0;
    __syncthreads();
    s[tid] += t;
    __syncthreads();
  }
  if (tid < NBKT) bucket_start[tid] = s[tid] - v;   // exclusive
  if (tid == 0) { bucket_start[NBKT] = N_EDGES; row_ptr[N_NODES] = N_EDGES; }
}

// ---------------- scatter edges into bucket-grouped order (atomic-free) ----------------
__global__ __launch_bounds__(256) void bucket_scatter(const int* __restrict__ src,
                                                      const int* __restrict__ dst,
                                                      const int* __restrict__ pos,
                                                      const int* __restrict__ bucket_start,
                                                      const int* __restrict__ base_tbl,
                                                      int* __restrict__ ebuf_src,
                                                      int* __restrict__ ebuf_ln) {
  int e = blockIdx.x * 256 + threadIdx.x;
  if (e >= N_EDGES) return;
  int d = dst[e];
  int b = d / NPB;
  int p = bucket_start[b] + base_tbl[(e / EPB) * NBKT + b] + pos[e];
  ebuf_src[p] = src[e];
  ebuf_ln[p] = d - b * NPB;   // local node 0..124
}

// ---------------- per-bucket CSR finalize: row_ptr + node-grouped csr_src ----------------
__global__ __launch_bounds__(256) void bucket_csr(const int* __restrict__ ebuf_src,
                                                  const int* __restrict__ ebuf_ln,
                                                  const int* __restrict__ bucket_start,
                                                  int* __restrict__ row_ptr,
                                                  int* __restrict__ csr_src) {
  __shared__ int cnt[128];
  int tid = threadIdx.x, b = blockIdx.x;
  int bs = bucket_start[b], be = bucket_start[b + 1];
  for (int i = tid; i < 128; i += 256) cnt[i] = 0;
  __syncthreads();
  int ln[6], lp[6];
#pragma unroll
  for (int j = 0; j < 6; ++j) {            // capacity 1536 edges; Binomial max ~870
    int p = bs + tid + j * 256;
    if (p < be) { ln[j] = ebuf_ln[p]; lp[j] = atomicAdd(&cnt[ln[j]], 1); }
  }
  __syncthreads();
  // inclusive scan over cnt[0..127]
  for (int off = 1; off < 128; off <<= 1) {
    int t = 0;
    if (tid < 128 && tid >= off) t = cnt[tid - off];
    __syncthreads();
    if (tid < 128) cnt[tid] += t;
    __syncthreads();
  }
  for (int i = tid; i < NPB; i += 256)
    row_ptr[b * NPB + i] = bs + (i ? cnt[i - 1] : 0);
#pragma unroll
  for (int j = 0; j < 6; ++j) {
    int p = bs + tid + j * 256;
    if (p < be) {
      int l = ln[j];
      csr_src[bs + (l ? cnt[l - 1] : 0) + lp[j]] = ebuf_src[p];
    }
  }
}

// ---------------- gather-mean, 128 bf16 cols: 16 threads/node, 8-wide predicated batches ----------------
__global__ __launch_bounds__(256) void aggregate128(const unsigned short* __restrict__ xb,
                                                    const int* __restrict__ row_ptr,
                                                    const int* __restrict__ csr_src,
                                                    unsigned short* __restrict__ agg, int n) {
  int t = blockIdx.x * blockDim.x + threadIdx.x;
  int node = t >> 4;
  int c = (t & 15) << 3;  // 8 bf16 per thread
  if (node >= n) return;
  int beg = row_ptr[node], end = row_ptr[node + 1];
  float acc[8];
#pragma unroll
  for (int j = 0; j < 8; ++j) acc[j] = 0.f;

  if (end > beg) {
    for (int e0 = beg; e0 < end; e0 += 8) {
      int idx[8];
#pragma unroll
      for (int p = 0; p < 8; ++p) idx[p] = csr_src[min(e0 + p, end - 1)];
      uint4 v[8];
#pragma unroll
      for (int p = 0; p < 8; ++p) v[p] = *(const uint4*)(xb + (size_t)idx[p] * K_DIM + c);
#pragma unroll
      for (int p = 0; p < 8; ++p) {
        float m = (e0 + p < end) ? 1.f : 0.f;
        unsigned u[4] = {v[p].x, v[p].y, v[p].z, v[p].w};
#pragma unroll
        for (int j = 0; j < 4; ++j) {
          acc[2 * j]     += m * __builtin_bit_cast(float, u[j] << 16);
          acc[2 * j + 1] += m * __builtin_bit_cast(float, u[j] & 0xffff0000u);
        }
      }
    }
  }
  float inv = 1.0f / (float)max(end - beg, 1);
  uint4 o;
  unsigned* op = (unsigned*)&o;
#pragma unroll
  for (int j = 0; j < 4; ++j) {
    unsigned lo = f2b(acc[2 * j] * inv);
    unsigned hi = f2b(acc[2 * j + 1] * inv);
    op[j] = lo | (hi << 16);
  }
  *(uint4*)(agg + (size_t)node * K_DIM + c) = o;
}

// ---------------- gather-mean-add, 64 bf16 cols -> out fp32: 8 threads/node, 8-wide batches ----------------
__global__ __launch_bounds__(256) void aggregate64_add(const unsigned short* __restrict__ g,
                                                       const int* __restrict__ row_ptr,
                                                       const int* __restrict__ csr_src,
                                                       float* __restrict__ out, int n) {
  int t = blockIdx.x * blockDim.x + threadIdx.x;
  int node = t >> 3;
  int c = (t & 7) << 3;  // 8 bf16 per thread
  if (node >= n) return;
  int beg = row_ptr[node], end = row_ptr[node + 1];
  float acc[8];
#pragma unroll
  for (int j = 0; j < 8; ++j) acc[j] = 0.f;

  if (end > beg) {
    for (int e0 = beg; e0 < end; e0 += 8) {
      int idx[8];
#pragma unroll
      for (int p = 0; p < 8; ++p) idx[p] = csr_src[min(e0 + p, end - 1)];
      uint4 v[8];
#pragma unroll
      for (int p = 0; p < 8; ++p) v[p] = *(const uint4*)(g + (size_t)idx[p] * M2 + c);
#pragma unroll
      for (int p = 0; p < 8; ++p) {
        float m = (e0 + p < end) ? 1.f : 0.f;
        unsigned u[4] = {v[p].x, v[p].y, v[p].z, v[p].w};
#pragma unroll
        for (int j = 0; j < 4; ++j) {
          acc[2 * j]     += m * __builtin_bit_cast(float, u[j] << 16);
          acc[2 * j + 1] += m * __builtin_bit_cast(float, u[j] & 0xffff0000u);
        }
      }
    }
  }
  float inv = 1.0f / (float)max(end - beg, 1);
  float* op = out + (size_t)node * M2 + c;
  float4 o0 = *(float4*)(op);
  float4 o1 = *(float4*)(op + 4);
  o0.x += acc[0] * inv; o0.y += acc[1] * inv; o0.z += acc[2] * inv; o0.w += acc[3] * inv;
  o1.x += acc[4] * inv; o1.y += acc[5] * inv; o1.z += acc[6] * inv; o1.w += acc[7] * inv;
  *(float4*)(op) = o0;
  *(float4*)(op + 4) = o1;
}

// stage one 64-node tile of x+agg (32 KB) into LDS dbuf half, swizzled source
__device__ __forceinline__ void stage_tile(const unsigned short* xb, const unsigned short* aggb,
                                           int t, char* dstbase, int tid, int wave, int N) {
#pragma unroll
  for (int it = 0; it < 2; ++it) {
    int L = it * 8192 + tid * 16;            // [0, 16384)
    int row = L >> 8;                        // 0..63
    int srb = (L & 255) ^ ((row & 7) << 4);  // inverse-swizzled source byte
    int node = t * 64 + row;
    if (node >= N) node = N - 1;             // clamp (garbage rows never stored)
    char* d = dstbase + it * 8192 + wave * 1024;  // wave-uniform; HW adds lane*16
    gload_lds16((const char*)xb + (size_t)node * 256 + srb, d);
    gload_lds16((const char*)aggb + (size_t)node * 256 + srb, d + 16384);
  }
}

// ---------------- fused both-layer GEMM (v5: persistent, everything via DMA+LDS) ----------------
// Confirmed working (round 6/7). Rule from v1-v4: any global->VGPR operand load feeding
// MFMA gets latency-serialized by the compiler; global_load_lds is the only reliably-batched
// path. Persistent blocks (grid=256, 1/CU, 512 thr), weights staged ONCE, x/agg 2x32K dbuf
// with one-tile-ahead DMA; raw lgkm-only barriers keep the prefetch DMA in flight.
__global__ __launch_bounds__(512, 2) void sage_fused_gemm(const unsigned short* __restrict__ xb,
                                                          const unsigned short* __restrict__ aggb,
                                                          const unsigned short* __restrict__ Ws1T,
                                                          const unsigned short* __restrict__ Wn1T,
                                                          const float* __restrict__ b1,
                                                          const unsigned short* __restrict__ Ws2T,
                                                          const unsigned short* __restrict__ Wn2T,
                                                          const float* __restrict__ b2,
                                                          float* __restrict__ out,
                                                          unsigned short* __restrict__ g, int N) {
  // [0,32K) Ws1T | [32K,64K) Wn1T | [64K,80K) Ws2T | [80K,96K) Wn2T | [96K,128K) buf0 | [128K,160K) buf1
  __shared__ char sL[163840];

  const int tid = threadIdx.x;
  const int wave = tid >> 6;
  const int lane = tid & 63;
  const int l15 = lane & 15;
  const int q = lane >> 4;
  const int nodeq = wave >> 1;     // 0..3 -> 16-node strip
  const int fhalf = wave & 1;      // phase-1 feat half / phase-2 output matrix
  const int fbase = fhalf * 64;

  // ---- prologue: stage all weights (96 KB) + first tile (once per block) ----
#pragma unroll
  for (int it = 0; it < 4; ++it) {           // W1: 2 x 32K
    int L = it * 8192 + tid * 16;
    int row = L >> 8;
    int srb = (L & 255) ^ ((row & 7) << 4);
    char* d = sL + it * 8192 + wave * 1024;
    gload_lds16((const char*)Ws1T + row * 256 + srb, d);
    gload_lds16((const char*)Wn1T + row * 256 + srb, d + 32768);
  }
#pragma unroll
  for (int it = 0; it < 2; ++it) {           // W2: 2 x 16K
    int L = it * 8192 + tid * 16;
    int row = L >> 8;
    int srb = (L & 255) ^ ((row & 7) << 4);
    char* d = sL + 65536 + it * 8192 + wave * 1024;
    gload_lds16((const char*)Ws2T + row * 256 + srb, d);
    gload_lds16((const char*)Wn2T + row * 256 + srb, d + 16384);
  }
  int tt = blockIdx.x;
  if (tt < NT_TILES) stage_tile(xb, aggb, tt, sL + 98304, tid, wave, N);

  // ---- biases: loop-invariant plain loads (hoisted; once per block) ----
  float4 bv1[4], bv2[4];
#pragma unroll
  for (int ft = 0; ft < 4; ++ft) {
    bv1[ft] = *(const float4*)(b1 + fbase + ft * 16 + q * 4);
    bv2[ft] = *(const float4*)(b2 + ft * 16 + q * 4);
  }

  // ---- persistent tile loop ----
  int li = 0;
  for (; tt < NT_TILES; tt += GEMM_GRID, ++li) {
    char* cur = sL + 98304 + (li & 1) * 32768;
    char* nxt = sL + 98304 + ((li + 1) & 1) * 32768;

    __syncthreads();  // B1: vmcnt(0) drain -> DMA(cur) complete; prev phase-2 LDS reads done

    if (tt + GEMM_GRID < NT_TILES)           // prefetch next tile (stays in flight across
      stage_tile(xb, aggb, tt + GEMM_GRID, nxt, tid, wave, N);  // the raw barriers below)

    // ---- phase 1: h1 = relu(x@Ws1 + agg@Wn1 + b1), operands all from LDS ----
    frag_cd acc[4];
#pragma unroll
    for (int ft = 0; ft < 4; ++ft) acc[ft] = (frag_cd)(0.f);

    const int xrow = nodeq * 16 + l15;
    const int xswz = (xrow & 7) << 4;
#pragma unroll
    for (int kb = 0; kb < 4; ++kb) {
      int base = kb * 64 + q * 16;
      frag_ab axk = *(const frag_ab*)(cur + xrow * 256 + (base ^ xswz));
      frag_ab agk = *(const frag_ab*)(cur + 16384 + xrow * 256 + (base ^ xswz));
      frag_ab fs[4], fn[4];
#pragma unroll
      for (int ft = 0; ft < 4; ++ft) {
        int wrow = fbase + ft * 16 + l15;
        int woff = base ^ ((wrow & 7) << 4);
        fs[ft] = *(const frag_ab*)(sL + wrow * 256 + woff);
        fn[ft] = *(const frag_ab*)(sL + 32768 + wrow * 256 + woff);
      }
#pragma unroll
      for (int ft = 0; ft < 4; ++ft) {
        acc[ft] = __builtin_amdgcn_mfma_f32_16x16x32_bf16(fs[ft], axk, acc[ft], 0, 0, 0);
        acc[ft] = __builtin_amdgcn_mfma_f32_16x16x32_bf16(fn[ft], agk, acc[ft], 0, 0, 0);
      }
    }

    lgkm_barrier();  // B2: all phase-1 x reads done before h1 overwrites (DMA stays in flight)

    // epilogue 1: relu(acc + b1) -> h1 (cur x region, same swizzle)
#pragma unroll
    for (int ft = 0; ft < 4; ++ft) {
      int f0 = fbase + ft * 16 + q * 4;
      ushort4 o;
      o.x = f2b(fmaxf(acc[ft][0] + bv1[ft].x, 0.f));
      o.y = f2b(fmaxf(acc[ft][1] + bv1[ft].y, 0.f));
      o.z = f2b(fmaxf(acc[ft][2] + bv1[ft].z, 0.f));
      o.w = f2b(fmaxf(acc[ft][3] + bv1[ft].w, 0.f));
      *(ushort4*)(cur + xrow * 256 + ((f0 * 2) ^ xswz)) = o;
    }

    lgkm_barrier();  // B3: h1 visible to all waves (DMA still in flight)

    // ---- phase 2: out = h1@Ws2 + b2 (fhalf 0), g = h1@Wn2 (fhalf 1) ----
    const char* w2b = sL + 65536 + fhalf * 16384;
    frag_cd acc2[4];
#pragma unroll
    for (int ft = 0; ft < 4; ++ft) acc2[ft] = (frag_cd)(0.f);

#pragma unroll
    for (int kb = 0; kb < 4; ++kb) {
      int base = kb * 64 + q * 16;
      frag_ab ah = *(const frag_ab*)(cur + xrow * 256 + (base ^ xswz));
      frag_ab w2[4];
#pragma unroll
      for (int ft = 0; ft < 4; ++ft) {
        int wr = ft * 16 + l15;
        w2[ft] = *(const frag_ab*)(w2b + wr * 256 + (base ^ ((wr & 7) << 4)));
      }
#pragma unroll
      for (int ft = 0; ft < 4; ++ft)
        acc2[ft] = __builtin_amdgcn_mfma_f32_16x16x32_bf16(w2[ft], ah, acc2[ft], 0, 0, 0);
    }

    int node = tt * 64 + nodeq * 16 + l15;
    if (node < N) {
      if (fhalf == 0) {
#pragma unroll
        for (int ft = 0; ft < 4; ++ft) {
          int f0 = ft * 16 + q * 4;
          float4 o;
          o.x = acc2[ft][0] + bv2[ft].x;
          o.y = acc2[ft][1] + bv2[ft].y;
          o.z = acc2[ft][2] + bv2[ft].z;
          o.w = acc2[ft][3] + bv2[ft].w;
          *(float4*)(out + (size_t)node * M2 + f0) = o;
        }
      } else {
#pragma unroll
        for (int ft = 0; ft < 4; ++ft) {
          int f0 = ft * 16 + q * 4;
          ushort4 o;
          o.x = f2b(acc2[ft][0]);
          o.y = f2b(acc2[ft][1]);
          o.z = f2b(acc2[ft][2]);
          o.w = f2b(acc2[ft][3]);
          *(ushort4*)(g + (size_t)node * M2 + f0) = o;
        }
      }
    }
  }
}

extern "C" void kernel_launch(void* const* d_in, const int* in_sizes, int n_in,
                              void* d_out, int out_size, void* d_ws, size_t ws_size,
                              hipStream_t stream) {
  const float* x   = (const float*)d_in[0];
  const int*   src = (const int*)d_in[1];
  const int*   dst = (const int*)d_in[2];
  const float* Ws1 = (const float*)d_in[3];
  const float* Wn1 = (const float*)d_in[4];
  const float* b1  = (const float*)d_in[5];
  const float* Ws2 = (const float*)d_in[6];
  const float* Wn2 = (const float*)d_in[7];
  const float* b2  = (const float*)d_in[8];
  float* out = (float*)d_out;

  char* ws = (char*)d_ws;
  size_t off = 0;
  auto alloc = [&](size_t bytes) {
    void* p = ws + off;
    off = (off + bytes + 4095) & ~(size_t)4095;
    return p;
  };
  int* row_ptr      = (int*)alloc((size_t)(N_NODES + 1) * 4);
  int* pos          = (int*)alloc((size_t)N_EDGES * 4);
  int* gbucket      = (int*)alloc((size_t)NBKT * 4);
  int* bucket_start = (int*)alloc((size_t)(NBKT + 1) * 4);
  int* base_tbl     = (int*)alloc((size_t)HIST_BLOCKS * NBKT * 4);
  int* ebuf_src     = (int*)alloc((size_t)N_EDGES * 4);
  int* ebuf_ln      = (int*)alloc((size_t)N_EDGES * 4);
  int* csr_src      = (int*)alloc((size_t)N_EDGES * 4);
  unsigned short* xb   = (unsigned short*)alloc((size_t)N_NODES * K_DIM * 2);
  unsigned short* aggb = (unsigned short*)alloc((size_t)N_NODES * K_DIM * 2);
  unsigned short* g    = (unsigned short*)alloc((size_t)N_NODES * M2 * 2);
  unsigned short* Ws1T = (unsigned short*)alloc((size_t)128 * 128 * 2);
  unsigned short* Wn1T = (unsigned short*)alloc((size_t)128 * 128 * 2);
  unsigned short* Ws2T = (unsigned short*)alloc((size_t)64 * 128 * 2);
  unsigned short* Wn2T = (unsigned short*)alloc((size_t)64 * 128 * 2);

  hipMemsetAsync(gbucket, 0, (size_t)NBKT * 4, stream);

  // fused: bucket hist (first, overlaps streaming) + x->bf16 + weight transposes
  conv_all<<<HIST_BLOCKS + XB_BLOCKS + WB_BLOCKS, 256, 0, stream>>>(
      x, xb, Ws1, Wn1, Ws2, Wn2, Ws1T, Wn1T, Ws2T, Wn2T, dst, pos, gbucket, base_tbl);

  // CSR build: bucket scan -> atomic-free scatter -> per-bucket finalize
  scan_buckets<<<1, 1024, 0, stream>>>(gbucket, bucket_start, row_ptr);
  bucket_scatter<<<(N_EDGES + 255) / 256, 256, 0, stream>>>(
      src, dst, pos, bucket_start, base_tbl, ebuf_src, ebuf_ln);
  bucket_csr<<<NBKT, 256, 0, stream>>>(ebuf_src, ebuf_ln, bucket_start, row_ptr, csr_src);

  // layer-1 aggregation (gather-mean, 8-wide predicated batches)
  {
    long t = (long)N_NODES * 16;
    aggregate128<<<(int)((t + 255) / 256), 256, 0, stream>>>(xb, row_ptr, csr_src, aggb, N_NODES);
  }

  // fused layer-1 + layer-2 GEMMs: persistent blocks, weights staged once, tile-ahead DMA
  sage_fused_gemm<<<GEMM_GRID, 512, 0, stream>>>(
      xb, aggb, Ws1T, Wn1T, b1, Ws2T, Wn2T, b2, out, g, N_NODES);

  // layer-2 aggregation (adds mean(g) into out)
  {
    long t = (long)N_NODES * 8;
    aggregate64_add<<<(int)((t + 255) / 256), 256, 0, stream>>>(g, row_ptr, csr_src, out, N_NODES);
  }
}